// Round 7
// baseline (729.295 us; speedup 1.0000x reference)
//
#include <hip/hip_runtime.h>
#include <hip/hip_bf16.h>

// B=16, N=1024, R=10, De=64, Dr=32, H=64, cat_in=960
// out[b,m,h] = relu( bias[h] + sum_r sum_n adj[b,r,m,n] * Yt[br,h,n] )
// Yt[br,h,n] = sum_d x[b,n,d]*W[h, r*96+d] + c[br,h]
// c[br,h]    = sum_d rel[br,d]*W[h, r*96+64+d]

typedef __bf16 bf16x8 __attribute__((ext_vector_type(8)));
typedef float  f32x4  __attribute__((ext_vector_type(4)));

// ---------------- prep kernel: c (fused) + Yt[br,h,n] (bf16, linear) ----------------
__global__ __launch_bounds__(256)
void rgcn_prep(const float* __restrict__ x, const float* __restrict__ rel,
               const float* __restrict__ W, __bf16* __restrict__ yt) {
    const int r = blockIdx.y, b = blockIdx.z;
    const int br = b * 10 + r;

    __shared__ float csh[64];
    if (threadIdx.x < 64) {
        const int h = threadIdx.x;
        const float* rp = rel + (size_t)br * 32;
        const float* wp = W + (size_t)h * 960 + r * 96 + 64;
        float a = 0.f;
#pragma unroll
        for (int d = 0; d < 32; ++d) a += rp[d] * wp[d];
        csh[h] = a;
    }
    __syncthreads();

    const int n = blockIdx.x * 256 + threadIdx.x;   // 0..1023
    float xr[64];
    const float* xp = x + ((size_t)b * 1024 + n) * 64;
#pragma unroll
    for (int j = 0; j < 16; ++j) {
        const float4 v = *(const float4*)(xp + j * 4);
        xr[j * 4 + 0] = v.x; xr[j * 4 + 1] = v.y;
        xr[j * 4 + 2] = v.z; xr[j * 4 + 3] = v.w;
    }

    const float* wbase = W + r * 96;                 // W[h*960 + r*96 + d]
    __bf16* yb = yt + ((size_t)br << 16) + n;        // Yt[br][h][n], linear
    for (int h = 0; h < 64; ++h) {                   // h,d wave-uniform -> W scalar loads
        float acc = csh[h];
        const float* wr = wbase + (size_t)h * 960;
#pragma unroll
        for (int d = 0; d < 64; ++d) acc += xr[d] * wr[d];
        yb[(size_t)h << 10] = (__bf16)acc;
    }
}

// ---------------- main kernel: barrier-free copy-like adj stream ----------------
// grid (16 b, 64 mslab), 512 thr = 8 waves. Block covers rows [ms*16, ms*16+16),
// accumulates ALL 10 relations in registers -> single final LDS k-reduce + write.
// NO barrier anywhere in the r-loop: the vmem queue is never drained.
// Wave w owns k in [w*128, (w+1)*128): its Y fragments = 64 VGPR, reloaded per r
// hf-STAGGERED (each quarter re-issued right after its last MFMA use), so every
// wait is a counted vmcnt with the next adj batch still in flight.
// Per r per wave: 8 adj dwordx4 (HBM, nt) + 16 Y dwordx4 (L2) + 16 MFMA.
// Frags (validated r1-r6): A lane=(m=lm, k=w*128+kc*32+g*8+j);
// B lane=(h=hf*16+lm, same k-map; k-perm cancels); C/D: h=lm, m=g*4+reg.
// XCD locality: linear block id = b + 16*ms -> XCD=b%8; Yt/XCD = 2*1.25 MB < L2.
__global__ __launch_bounds__(512, 2)
void rgcn_main(const float* __restrict__ adj, const __bf16* __restrict__ yt,
               const float* __restrict__ bias, float* __restrict__ dst) {
    const int b  = blockIdx.x;       // 0..15
    const int ms = blockIdx.y;       // 0..63
    const int tid = threadIdx.x;
    const int w = tid >> 6, lane = tid & 63;
    const int g = lane >> 4, lm = lane & 15;

    const float* abase = adj + (((size_t)(b * 10) * 1024 + ms * 16 + lm) << 10)
                       + w * 128 + g * 8;
    const __bf16* ybase = yt + ((size_t)(b * 10) << 16) + ((size_t)lm << 10)
                        + w * 128 + g * 8;

    f32x4 pf[8];        // raw adj batch for current r (32 B/lane per kc)
    bf16x8 yq[4][4];    // Y fragments [hf][kc] for this wave's k-share
    f32x4 acc[4] = {};

#define ISSUE_A(rr) { const float* ap = abase + (size_t)(rr) * 1048576;          \
    _Pragma("unroll") for (int kc = 0; kc < 4; ++kc) {                           \
        pf[2*kc]   = __builtin_nontemporal_load((const f32x4*)(ap + kc * 32));   \
        pf[2*kc+1] = __builtin_nontemporal_load((const f32x4*)(ap + kc * 32 + 4)); } }

#define ISSUE_YQ(hf_, rr) { const __bf16* yp = ybase + (((size_t)(rr)) << 16)    \
                             + (size_t)(hf_) * 16384;                            \
    _Pragma("unroll") for (int kc = 0; kc < 4; ++kc)                             \
        yq[hf_][kc] = *(const bf16x8*)(yp + kc * 32); }

    // prologue: relation 0 adj + Y
    ISSUE_A(0)
#pragma unroll
    for (int hf = 0; hf < 4; ++hf) ISSUE_YQ(hf, 0)

    for (int r = 0; r < 10; ++r) {
        // convert current adj batch (counted wait: Y(r) + nothing newer drained)
        bf16x8 av[4];
#pragma unroll
        for (int kc = 0; kc < 4; ++kc)
#pragma unroll
            for (int e = 0; e < 4; ++e) {
                av[kc][e]     = (__bf16)pf[2*kc][e];
                av[kc][4 + e] = (__bf16)pf[2*kc+1][e];
            }
        if (r < 9) ISSUE_A(r + 1)        // next HBM batch in flight during MFMAs

#pragma unroll
        for (int hf = 0; hf < 4; ++hf) {
#pragma unroll
            for (int kc = 0; kc < 4; ++kc)
                acc[hf] = __builtin_amdgcn_mfma_f32_16x16x32_bf16(
                              av[kc], yq[hf][kc], acc[hf], 0, 0, 0);
            if (r < 9) ISSUE_YQ(hf, r + 1)   // quarter dead now; counted reload
        }
    }
#undef ISSUE_A
#undef ISSUE_YQ

    // ---- single end-of-kernel cross-wave k-reduction ----
    __shared__ float shR[8 * 1024];
#pragma unroll
    for (int hf = 0; hf < 4; ++hf)
#pragma unroll
        for (int reg = 0; reg < 4; ++reg)
            shR[w * 1024 + (g * 4 + reg) * 64 + hf * 16 + lm] = acc[hf][reg];
    __syncthreads();

    {
        const int e0 = tid * 2;                      // element in [16 m][64 h]
        float s0 = 0.f, s1 = 0.f;
#pragma unroll
        for (int s = 0; s < 8; ++s) {
            s0 += shR[s * 1024 + e0];
            s1 += shR[s * 1024 + e0 + 1];
        }
        const int h0 = e0 & 63;
        s0 = fmaxf(s0 + bias[h0], 0.f);
        s1 = fmaxf(s1 + bias[h0 + 1], 0.f);
        float2 o = {s0, s1};
        *(float2*)(dst + (((size_t)b << 10) + ms * 16) * 64 + e0) = o;
    }
}

extern "C" void kernel_launch(void* const* d_in, const int* in_sizes, int n_in,
                              void* d_out, int out_size, void* d_ws, size_t ws_size,
                              hipStream_t stream) {
    const float* x   = (const float*)d_in[0];   // [16,1024,64]
    const float* rel = (const float*)d_in[1];   // [16,10,32]
    const float* adj = (const float*)d_in[2];   // [16,10,1024,1024]
    const float* W0  = (const float*)d_in[3];   // [64,960]
    const float* b0  = (const float*)d_in[4];   // [64]
    const float* W1  = (const float*)d_in[5];
    const float* b1  = (const float*)d_in[6];
    float* out = (float*)d_out;                 // [16,1024,64]

    char* ws = (char*)d_ws;
    __bf16* Yt = (__bf16*)ws;                   // 20,971,520 B (160 x 64 x 1024 bf16)
    float* x2  = (float*)(ws + 20971520);       //  4,194,304 B (layer-1 activations)

    for (int layer = 0; layer < 2; ++layer) {
        const float* xin  = layer ? x2 : x;
        const float* W    = layer ? W1 : W0;
        const float* bias = layer ? b1 : b0;
        float* dst        = layer ? out : x2;

        rgcn_prep<<<dim3(4, 10, 16), 256, 0, stream>>>(xin, rel, W, Yt);
        rgcn_main<<<dim3(16, 64), 512, 0, stream>>>(adj, Yt, bias, dst);
    }
}

// Round 8
// 629.696 us; speedup vs baseline: 1.1582x; 1.1582x over previous
//
#include <hip/hip_runtime.h>
#include <hip/hip_bf16.h>

// B=16, N=1024, R=10, De=64, Dr=32, H=64, cat_in=960
// out[b,m,h] = relu( bias[h] + sum_r sum_n adj[b,r,m,n] * Yt[br,h,n] )
// Yt[br,h,n] = sum_d x[b,n,d]*W[h, r*96+d] + c[br,h]
// c[br,h]    = sum_d rel[br,d]*W[h, r*96+64+d]
//
// Layer 1 main reads fp32 adj, converts to bf16 frags for MFMA, and WRITES the
// bf16 frags to workspace (write path is otherwise idle). Layer 2 main reads
// the bf16 copy -> half the adj read bytes, no cvt. ws ~2.7 GB (fill evidence).

typedef __bf16 bf16x8 __attribute__((ext_vector_type(8)));
typedef float  f32x4  __attribute__((ext_vector_type(4)));
typedef float  f32x8  __attribute__((ext_vector_type(8)));

// ---------------- prep kernel: c (fused) + Yt[br,h,n] (bf16, linear) ----------------
__global__ __launch_bounds__(256)
void rgcn_prep(const float* __restrict__ x, const float* __restrict__ rel,
               const float* __restrict__ W, __bf16* __restrict__ yt) {
    const int r = blockIdx.y, b = blockIdx.z;
    const int br = b * 10 + r;

    __shared__ float csh[64];
    if (threadIdx.x < 64) {
        const int h = threadIdx.x;
        const float* rp = rel + (size_t)br * 32;
        const float* wp = W + (size_t)h * 960 + r * 96 + 64;
        float a = 0.f;
#pragma unroll
        for (int d = 0; d < 32; ++d) a += rp[d] * wp[d];
        csh[h] = a;
    }
    __syncthreads();

    const int n = blockIdx.x * 256 + threadIdx.x;   // 0..1023
    float xr[64];
    const float* xp = x + ((size_t)b * 1024 + n) * 64;
#pragma unroll
    for (int j = 0; j < 16; ++j) {
        const float4 v = *(const float4*)(xp + j * 4);
        xr[j * 4 + 0] = v.x; xr[j * 4 + 1] = v.y;
        xr[j * 4 + 2] = v.z; xr[j * 4 + 3] = v.w;
    }

    const float* wbase = W + r * 96;                 // W[h*960 + r*96 + d]
    __bf16* yb = yt + ((size_t)br << 16) + n;        // Yt[br][h][n], linear
    for (int h = 0; h < 64; ++h) {                   // h,d wave-uniform -> W scalar loads
        float acc = csh[h];
        const float* wr = wbase + (size_t)h * 960;
#pragma unroll
        for (int d = 0; d < 64; ++d) acc += xr[d] * wr[d];
        yb[(size_t)h << 10] = (__bf16)acc;
    }
}

// ---------------- layer-1 main: fp32 adj -> MFMA, + bf16 frag writeback ----------------
// Round-1 structure (best measured). grid (8 mtile, 5 rg, 16 b), 256 thr = 4 waves,
// wave owns 32m x 64h, NR=2 relations per block.
// A-frag: adj row (lane&15 [+16]), k=(lane>>4)*8+j ; B-frag same k-map (perm cancels).
// C/D: col=lane&15 (h), row=(lane>>4)*4+reg (m) — validated rounds 1-7.
// abf region per (br,mtile): 131072 bf16 = 256 KB; slot ((c*4+w)*2+s)*512 + lane*8.
__global__ __launch_bounds__(256, 2)
void rgcn_main1(const float* __restrict__ adj, const __bf16* __restrict__ yt,
                float* __restrict__ partial, __bf16* __restrict__ abf) {
    const int mtile = blockIdx.x, rg = blockIdx.y, b = blockIdx.z;
    const int w = threadIdx.x >> 6, lane = threadIdx.x & 63;
    const int g = lane >> 4, lm = lane & 15;
    const int mbase = mtile * 128 + w * 32;

    f32x4 acc[2][4] = {};

    for (int rr = 0; rr < 2; ++rr) {
        const int br = b * 10 + rg * 2 + rr;
        const float*  a0 = adj + (((size_t)br * 1024 + mbase + lm) << 10) + g * 8;
        const __bf16* y0 = yt  + (((size_t)br * 64 + lm) << 10) + g * 8;
        __bf16* ab = abf + ((size_t)(br * 8 + mtile) << 17);

        for (int n0 = 0; n0 < 1024; n0 += 32) {
            const f32x8 v0 = *(const f32x8*)(a0 + n0);
            const f32x8 v1 = *(const f32x8*)(a0 + (16 << 10) + n0);
            bf16x8 av0, av1;
#pragma unroll
            for (int j = 0; j < 8; ++j) {
                av0[j] = (__bf16)v0[j];
                av1[j] = (__bf16)v1[j];
            }
            const int c = n0 >> 5;
            *(bf16x8*)(ab + ((c * 8 + w * 2 + 0) << 9) + lane * 8) = av0;
            *(bf16x8*)(ab + ((c * 8 + w * 2 + 1) << 9) + lane * 8) = av1;
#pragma unroll
            for (int hf = 0; hf < 4; ++hf) {
                const bf16x8 bv = *(const bf16x8*)(y0 + hf * 16384 + n0);
                acc[0][hf] = __builtin_amdgcn_mfma_f32_16x16x32_bf16(av0, bv, acc[0][hf], 0, 0, 0);
                acc[1][hf] = __builtin_amdgcn_mfma_f32_16x16x32_bf16(av1, bv, acc[1][hf], 0, 0, 0);
            }
        }
    }

    float* pb = partial + (((size_t)rg * 16 + b) << 16) + (size_t)mbase * 64;
#pragma unroll
    for (int mf = 0; mf < 2; ++mf)
#pragma unroll
        for (int hf = 0; hf < 4; ++hf)
#pragma unroll
            for (int reg = 0; reg < 4; ++reg) {
                const int m = mf * 16 + g * 4 + reg;
                const int h = hf * 16 + lm;
                pb[((size_t)m << 6) + h] = acc[mf][hf][reg];
            }
}

// ---------------- layer-2 main: bf16 adj frags direct from workspace ----------------
__global__ __launch_bounds__(256, 2)
void rgcn_main2(const __bf16* __restrict__ abf, const __bf16* __restrict__ yt,
                float* __restrict__ partial) {
    const int mtile = blockIdx.x, rg = blockIdx.y, b = blockIdx.z;
    const int w = threadIdx.x >> 6, lane = threadIdx.x & 63;
    const int g = lane >> 4, lm = lane & 15;
    const int mbase = mtile * 128 + w * 32;

    f32x4 acc[2][4] = {};

    for (int rr = 0; rr < 2; ++rr) {
        const int br = b * 10 + rg * 2 + rr;
        const __bf16* y0 = yt + (((size_t)br * 64 + lm) << 10) + g * 8;
        const __bf16* ab = abf + ((size_t)(br * 8 + mtile) << 17);

        for (int n0 = 0; n0 < 1024; n0 += 32) {
            const int c = n0 >> 5;
            const bf16x8 av0 = *(const bf16x8*)(ab + ((c * 8 + w * 2 + 0) << 9) + lane * 8);
            const bf16x8 av1 = *(const bf16x8*)(ab + ((c * 8 + w * 2 + 1) << 9) + lane * 8);
#pragma unroll
            for (int hf = 0; hf < 4; ++hf) {
                const bf16x8 bv = *(const bf16x8*)(y0 + hf * 16384 + n0);
                acc[0][hf] = __builtin_amdgcn_mfma_f32_16x16x32_bf16(av0, bv, acc[0][hf], 0, 0, 0);
                acc[1][hf] = __builtin_amdgcn_mfma_f32_16x16x32_bf16(av1, bv, acc[1][hf], 0, 0, 0);
            }
        }
    }

    float* pb = partial + (((size_t)rg * 16 + b) << 16) + (size_t)mbase * 64;
#pragma unroll
    for (int mf = 0; mf < 2; ++mf)
#pragma unroll
        for (int hf = 0; hf < 4; ++hf)
#pragma unroll
            for (int reg = 0; reg < 4; ++reg) {
                const int m = mf * 16 + g * 4 + reg;
                const int h = hf * 16 + lm;
                pb[((size_t)m << 6) + h] = acc[mf][hf][reg];
            }
}

// ---------------- fallback main (small ws): fp32, all 10 r, fused epilogue ----------------
__global__ __launch_bounds__(256, 2)
void rgcn_mainF(const float* __restrict__ adj, const __bf16* __restrict__ yt,
                const float* __restrict__ bias, float* __restrict__ dst) {
    const int mtile = blockIdx.x, b = blockIdx.z;
    const int w = threadIdx.x >> 6, lane = threadIdx.x & 63;
    const int g = lane >> 4, lm = lane & 15;
    const int mbase = mtile * 128 + w * 32;

    f32x4 acc[2][4] = {};
    for (int r = 0; r < 10; ++r) {
        const int br = b * 10 + r;
        const float*  a0 = adj + (((size_t)br * 1024 + mbase + lm) << 10) + g * 8;
        const __bf16* y0 = yt  + (((size_t)br * 64 + lm) << 10) + g * 8;
        for (int n0 = 0; n0 < 1024; n0 += 32) {
            const f32x8 v0 = *(const f32x8*)(a0 + n0);
            const f32x8 v1 = *(const f32x8*)(a0 + (16 << 10) + n0);
            bf16x8 av0, av1;
#pragma unroll
            for (int j = 0; j < 8; ++j) { av0[j] = (__bf16)v0[j]; av1[j] = (__bf16)v1[j]; }
#pragma unroll
            for (int hf = 0; hf < 4; ++hf) {
                const bf16x8 bv = *(const bf16x8*)(y0 + hf * 16384 + n0);
                acc[0][hf] = __builtin_amdgcn_mfma_f32_16x16x32_bf16(av0, bv, acc[0][hf], 0, 0, 0);
                acc[1][hf] = __builtin_amdgcn_mfma_f32_16x16x32_bf16(av1, bv, acc[1][hf], 0, 0, 0);
            }
        }
    }
    float bvals[4];
#pragma unroll
    for (int hf = 0; hf < 4; ++hf) bvals[hf] = bias[hf * 16 + lm];
    float* db = dst + (((size_t)b * 1024 + mbase)) * 64;
#pragma unroll
    for (int mf = 0; mf < 2; ++mf)
#pragma unroll
        for (int hf = 0; hf < 4; ++hf)
#pragma unroll
            for (int reg = 0; reg < 4; ++reg) {
                const int m = mf * 16 + g * 4 + reg;
                const int h = hf * 16 + lm;
                db[((size_t)m << 6) + h] = fmaxf(acc[mf][hf][reg] + bvals[hf], 0.f);
            }
}

// ---------------- epilogue: sum 5 partial slices + bias + relu ----------------
__global__ __launch_bounds__(256)
void rgcn_epi(const float* __restrict__ partial, const float* __restrict__ bias,
              float* __restrict__ dst) {
    const size_t i = (size_t)blockIdx.x * 256 + threadIdx.x;  // f32x4 index, 262144 total
    const size_t off = i * 4;                                  // float idx into [16][1024][64]
    f32x4 s = {};
#pragma unroll
    for (int p = 0; p < 5; ++p)
        s += *(const f32x4*)(partial + (size_t)p * 1048576 + off);
    const f32x4 bv = *(const f32x4*)(bias + (int)(off & 63));
#pragma unroll
    for (int j = 0; j < 4; ++j) s[j] = fmaxf(s[j] + bv[j], 0.f);
    *(f32x4*)(dst + off) = s;
}

extern "C" void kernel_launch(void* const* d_in, const int* in_sizes, int n_in,
                              void* d_out, int out_size, void* d_ws, size_t ws_size,
                              hipStream_t stream) {
    const float* x   = (const float*)d_in[0];   // [16,1024,64]
    const float* rel = (const float*)d_in[1];   // [16,10,32]
    const float* adj = (const float*)d_in[2];   // [16,10,1024,1024]
    const float* W0  = (const float*)d_in[3];   // [64,960]
    const float* b0  = (const float*)d_in[4];   // [64]
    const float* W1  = (const float*)d_in[5];
    const float* b1  = (const float*)d_in[6];
    float* out = (float*)d_out;                 // [16,1024,64]

    char* ws = (char*)d_ws;
    __bf16* Yt   = (__bf16*)ws;                 // 20,971,520 B (160 x 64 x 1024 bf16)
    float*  x2   = (float*)(ws + 20971520);     //  4,194,304 B (layer-1 activations)
    float*  part = (float*)(ws + 25165824);     // 20,971,520 B (5 x 16 x 65536 f32)
    __bf16* abf  = (__bf16*)(ws + 46137344);    // 335,544,320 B (bf16 adj frag copy)
    const bool big = ws_size >= 381681664u;     // all of the above

    if (big) {
        // layer 1: fp32 adj -> out1 (x2), + bf16 frag writeback
        rgcn_prep<<<dim3(4, 10, 16), 256, 0, stream>>>(x, rel, W0, Yt);
        rgcn_main1<<<dim3(8, 5, 16), 256, 0, stream>>>(adj, Yt, part, abf);
        rgcn_epi<<<1024, 256, 0, stream>>>(part, b0, x2);
        // layer 2: bf16 adj copy -> out
        rgcn_prep<<<dim3(4, 10, 16), 256, 0, stream>>>(x2, rel, W1, Yt);
        rgcn_main2<<<dim3(8, 5, 16), 256, 0, stream>>>(abf, Yt, part);
        rgcn_epi<<<1024, 256, 0, stream>>>(part, b1, out);
    } else {
        for (int layer = 0; layer < 2; ++layer) {
            const float* xin  = layer ? x2 : x;
            const float* W    = layer ? W1 : W0;
            const float* bias = layer ? b1 : b0;
            float* dst        = layer ? out : x2;
            rgcn_prep<<<dim3(4, 10, 16), 256, 0, stream>>>(xin, rel, W, Yt);
            rgcn_mainF<<<dim3(8, 1, 16), 256, 0, stream>>>(adj, Yt, bias, dst);
        }
    }
}